// Round 9
// baseline (231.719 us; speedup 1.0000x reference)
//
#include <hip/hip_runtime.h>
#include <hip/hip_fp16.h>

// VariationalGCNEncoder: N=50000 nodes, E=600000 edges, 128->128(relu)->2x64
// out = mu (50000x64) then logstd (50000x64), flat concat.
//
// R1: hierarchical scan. R2: float4 gather aggregate, dis pre-scaling.
// R3: LDS-tile VALU GEMM. R4: fp16 aggregation operand (row=256B).
// R5: MFMA fp16 GEMM. R6: global fp16 W^T prep, swapped MFMA operands,
//     quarter-wave aggregate. R7: 1 group/block gemm, unroll-8 gather.
// R8: agg2+gemm2 FUSED: block aggregates 64 nodes into LDS fp16 (ZL, stride
//     136 like WL), one sync, then gemm2 MFMA phase reads fragments from
//     LDS. Deletes bufCh (12.8MB write + 12.8MB read) and one dispatch.

#define N_NODES 50000
#define N_EDGES 600000
#define MU_SIZE (N_NODES * 64)
#define SCAN_BLOCKS 200
#define SCAN_CHUNK 250  // SCAN_BLOCKS * SCAN_CHUNK == N_NODES
#define WT_S 136        // LDS row stride (halves), 272B: 2-way bank alias only

typedef _Float16 half8 __attribute__((ext_vector_type(8)));
typedef _Float16 half4 __attribute__((ext_vector_type(4)));
typedef float floatx4 __attribute__((ext_vector_type(4)));

union H8 { __half2 h2[4]; float4 f4; };

// Zero counts+fillcnt (contiguous 100000 ints) and build fp16 transposed
// weights: W1T[n][k] = fp16(W1[k][n]); W2T[n][k] = fp16([Wmu|Wls][k][n]).
__global__ __launch_bounds__(256) void prep_zero_kernel(const float* __restrict__ W1,
                                                        const float* __restrict__ Wmu,
                                                        const float* __restrict__ Wls,
                                                        _Float16* __restrict__ W1T,
                                                        _Float16* __restrict__ W2T,
                                                        int* __restrict__ zero_base) {
  int idx = blockIdx.x * 256 + threadIdx.x;  // grid 128 -> 32768 threads
  for (int i = idx; i < 2 * N_NODES; i += 32768) zero_base[i] = 0;
  int e = idx & 16383;
  int n = e >> 7, k = e & 127;
  if (idx < 16384) {
    W1T[e] = (_Float16)W1[k * 128 + n];
  } else {
    float w = (n < 64) ? Wmu[k * 64 + n] : Wls[k * 64 + (n - 64)];
    W2T[e] = (_Float16)w;
  }
}

__global__ __launch_bounds__(256) void count_kernel(const int* __restrict__ col,
                                                    int* __restrict__ counts, int e) {
  int i = blockIdx.x * 256 + threadIdx.x;
  if (i < e) atomicAdd(&counts[col[i]], 1);
}

// Per-block partial sums of counts (250 elems/block) + dis = rsqrt(deg+1)
__global__ __launch_bounds__(256) void blocksum_dis_kernel(const int* __restrict__ counts,
                                                           float* __restrict__ dis,
                                                           int* __restrict__ blocksums) {
  __shared__ int red[4];
  int b = blockIdx.x, t = threadIdx.x;
  int i = b * SCAN_CHUNK + t;
  int c = 0;
  if (t < SCAN_CHUNK) {
    c = counts[i];
    dis[i] = rsqrtf((float)(c + 1));  // +1 self-loop => deg >= 1 always
  }
  int s = c;
#pragma unroll
  for (int off = 32; off > 0; off >>= 1) s += __shfl_down(s, off, 64);
  if ((t & 63) == 0) red[t >> 6] = s;
  __syncthreads();
  if (t == 0) blocksums[b] = red[0] + red[1] + red[2] + red[3];
}

// Each block: scan the 200 blocksums in LDS for its exclusive base, then
// scan its own 250 counts and write exclusive offsets.
__global__ __launch_bounds__(256) void offsets_kernel(const int* __restrict__ counts,
                                                      const int* __restrict__ blocksums,
                                                      int* __restrict__ offsets) {
  __shared__ int sb[256];
  __shared__ int loc[256];
  int b = blockIdx.x, t = threadIdx.x;
  sb[t] = (t < SCAN_BLOCKS) ? blocksums[t] : 0;
  __syncthreads();
#pragma unroll
  for (int off = 1; off < 256; off <<= 1) {
    int v = (t >= off) ? sb[t - off] : 0;
    __syncthreads();
    sb[t] += v;
    __syncthreads();
  }
  int base = (b == 0) ? 0 : sb[b - 1];
  int i = b * SCAN_CHUNK + t;
  int c = (t < SCAN_CHUNK) ? counts[i] : 0;
  loc[t] = c;
  __syncthreads();
#pragma unroll
  for (int off = 1; off < 256; off <<= 1) {
    int v = (t >= off) ? loc[t - off] : 0;
    __syncthreads();
    loc[t] += v;
    __syncthreads();
  }
  if (t < SCAN_CHUNK) offsets[i] = base + loc[t] - c;  // exclusive
  if (b == SCAN_BLOCKS - 1 && t == SCAN_CHUNK - 1) offsets[N_NODES] = base + loc[t];
}

__global__ __launch_bounds__(256) void fill_kernel(const int* __restrict__ row,
                                                   const int* __restrict__ col,
                                                   const int* __restrict__ offsets,
                                                   int* __restrict__ fillcnt,
                                                   int* __restrict__ srcidx, int e) {
  int i = blockIdx.x * 256 + threadIdx.x;
  if (i < e) {
    int c = col[i];
    int pos = offsets[c] + atomicAdd(&fillcnt[c], 1);
    srcidx[pos] = row[i];
  }
}

// MFMA GEMM1, M=50000 nodes, K=128, 128 output feats. Block = 4 waves =
// 64 nodes. A = W^T tile (16 feats x 32 k, LDS), B = X^T (k-contiguous).
// D: lane(q,m) -> node m, feats 16f+4q..+3 (consecutive -> vector stores).
// out fp16: Yh[node] = dis[node] * (X @ W1)[node]
__global__ __launch_bounds__(256) void gemm1_mfma_kernel(const float* __restrict__ X,
                                                         const _Float16* __restrict__ WT,
                                                         const float* __restrict__ dis,
                                                         _Float16* __restrict__ Yh) {
  __shared__ _Float16 WL[128 * WT_S];  // 34 KB

  int t = threadIdx.x;
  for (int idx = t; idx < 128 * 16; idx += 256) {
    int n = idx >> 4, kk = (idx & 15) * 8;
    *(half8*)&WL[n * WT_S + kk] = *(const half8*)&WT[n * 128 + kk];
  }
  __syncthreads();

  int wid = t >> 6, lane = t & 63;
  int q = lane >> 4, m = lane & 15;

  int node = blockIdx.x * 64 + wid * 16 + m;
  size_t nr = (size_t)min(node, N_NODES - 1);
  bool valid = node < N_NODES;

  half8 xfrag[4];
#pragma unroll
  for (int c = 0; c < 4; ++c) {
    const float* ap = &X[nr * 128 + 32 * c + 8 * q];
    float4 a0 = *(const float4*)ap;
    float4 a1 = *(const float4*)(ap + 4);
    half8 af = {(_Float16)a0.x, (_Float16)a0.y, (_Float16)a0.z, (_Float16)a0.w,
                (_Float16)a1.x, (_Float16)a1.y, (_Float16)a1.z, (_Float16)a1.w};
    xfrag[c] = af;
  }
  float dnode = dis[nr];

#pragma unroll
  for (int f = 0; f < 8; ++f) {
    floatx4 acc = {0.f, 0.f, 0.f, 0.f};
#pragma unroll
    for (int c = 0; c < 4; ++c) {
      half8 wfrag = *(const half8*)&WL[(16 * f + m) * WT_S + 32 * c + 8 * q];
      acc = __builtin_amdgcn_mfma_f32_16x16x32_f16(wfrag, xfrag[c], acc, 0, 0, 0);
    }
    int fbase = 16 * f + 4 * q;
    if (valid) {
      half4 o = {(_Float16)(acc[0] * dnode), (_Float16)(acc[1] * dnode),
                 (_Float16)(acc[2] * dnode), (_Float16)(acc[3] * dnode)};
      *(half4*)&Yh[(size_t)node * 128 + fbase] = o;
    }
  }
}

// agg1: input rows fp16 pre-scaled Hs[i]=fp16(dis_i*H_i), fp32 accumulate.
// out[i] = fp16( di * relu(di*(sum Hs[r] + Hs[i]) + b) )   (re-scaled)
// One quarter-wave (16 lanes x 16B) per node; no cross-lane reduce.
__global__ __launch_bounds__(256) void aggregate1_kernel(const __half* __restrict__ Hs,
                                                         const int* __restrict__ offsets,
                                                         const int* __restrict__ srcidx,
                                                         const float* __restrict__ dis,
                                                         const float* __restrict__ bias,
                                                         __half* __restrict__ outH, int n) {
  int wid = threadIdx.x >> 6, lane = threadIdx.x & 63;
  int q = lane >> 4, ql = lane & 15;
  int i = blockIdx.x * 16 + wid * 4 + q;
  if (i >= n) return;
  float di = dis[i];
  float4 selfv = ((const float4*)(Hs + (size_t)i * 128))[ql];
  float acc[8] = {0.f, 0.f, 0.f, 0.f, 0.f, 0.f, 0.f, 0.f};
  int k = offsets[i], end = offsets[i + 1];
  for (; k + 7 < end; k += 8) {
    int r[8];
#pragma unroll
    for (int u = 0; u < 8; ++u) r[u] = srcidx[k + u];
    float4 v[8];
#pragma unroll
    for (int u = 0; u < 8; ++u) v[u] = ((const float4*)(Hs + (size_t)r[u] * 128))[ql];
#pragma unroll
    for (int u = 0; u < 8; ++u) {
      const __half2* a = (const __half2*)&v[u];
#pragma unroll
      for (int j = 0; j < 4; ++j) {
        float2 f = __half22float2(a[j]);
        acc[2 * j] += f.x;
        acc[2 * j + 1] += f.y;
      }
    }
  }
  for (; k + 3 < end; k += 4) {
    int r[4];
#pragma unroll
    for (int u = 0; u < 4; ++u) r[u] = srcidx[k + u];
    float4 v[4];
#pragma unroll
    for (int u = 0; u < 4; ++u) v[u] = ((const float4*)(Hs + (size_t)r[u] * 128))[ql];
#pragma unroll
    for (int u = 0; u < 4; ++u) {
      const __half2* a = (const __half2*)&v[u];
#pragma unroll
      for (int j = 0; j < 4; ++j) {
        float2 f = __half22float2(a[j]);
        acc[2 * j] += f.x;
        acc[2 * j + 1] += f.y;
      }
    }
  }
  for (; k < end; ++k) {
    int r0 = srcidx[k];
    float4 v0 = ((const float4*)(Hs + (size_t)r0 * 128))[ql];
    const __half2* a0 = (const __half2*)&v0;
#pragma unroll
    for (int j = 0; j < 4; ++j) {
      float2 f0 = __half22float2(a0[j]);
      acc[2 * j] += f0.x;
      acc[2 * j + 1] += f0.y;
    }
  }
  const __half2* sh = (const __half2*)&selfv;
  float s[8];
#pragma unroll
  for (int j = 0; j < 4; ++j) {
    float2 f = __half22float2(sh[j]);
    s[2 * j] = di * (acc[2 * j] + f.x);
    s[2 * j + 1] = di * (acc[2 * j + 1] + f.y);
  }
  float4 b0 = ((const float4*)bias)[2 * ql];
  float4 b1 = ((const float4*)bias)[2 * ql + 1];
  H8 u;
  u.h2[0] = __float22half2_rn(
      make_float2(di * fmaxf(s[0] + b0.x, 0.f), di * fmaxf(s[1] + b0.y, 0.f)));
  u.h2[1] = __float22half2_rn(
      make_float2(di * fmaxf(s[2] + b0.z, 0.f), di * fmaxf(s[3] + b0.w, 0.f)));
  u.h2[2] = __float22half2_rn(
      make_float2(di * fmaxf(s[4] + b1.x, 0.f), di * fmaxf(s[5] + b1.y, 0.f)));
  u.h2[3] = __float22half2_rn(
      make_float2(di * fmaxf(s[6] + b1.z, 0.f), di * fmaxf(s[7] + b1.w, 0.f)));
  ((float4*)(outH + (size_t)i * 128))[ql] = u.f4;
}

// FUSED agg2 + gemm2. Block = 256 threads handles 64 nodes.
// Phase 1: 16 quarter-waves aggregate 4 nodes each:
//   z_i = di*(sum_{r in N(i)} Hs[r] + Hs[i])  -> fp16 into LDS ZL[nl][.]
// Phase 2 (after one sync): gemm2 MFMA with A = W2^T (LDS WL), B = ZL rows;
//   out[node*64+c] = (z @ Wmu)[c] + bmu[c]; out[MU + node*64+c] likewise.
__global__ __launch_bounds__(256) void agg2_gemm2_kernel(const __half* __restrict__ Hs,
                                                         const int* __restrict__ offsets,
                                                         const int* __restrict__ srcidx,
                                                         const float* __restrict__ dis,
                                                         const _Float16* __restrict__ W2T,
                                                         const float* __restrict__ bmu,
                                                         const float* __restrict__ bls,
                                                         float* __restrict__ out) {
  __shared__ _Float16 WL[128 * WT_S];  // 34 KB
  __shared__ _Float16 ZL[64 * WT_S];   // 17 KB

  int t = threadIdx.x;
  // stage W2^T
  for (int idx = t; idx < 128 * 16; idx += 256) {
    int n = idx >> 4, kk = (idx & 15) * 8;
    *(half8*)&WL[n * WT_S + kk] = *(const half8*)&W2T[n * 128 + kk];
  }

  // phase 1: aggregate 64 nodes (quarter-wave per node, 4 rounds)
  int qw = t >> 4, ql = t & 15;
  int base = blockIdx.x * 64;
#pragma unroll
  for (int it = 0; it < 4; ++it) {
    int nl = qw * 4 + it;  // local node 0..63
    int i = base + nl;
    H8 u;
    if (i < N_NODES) {
      float di = dis[i];
      float4 selfv = ((const float4*)(Hs + (size_t)i * 128))[ql];
      float acc[8] = {0.f, 0.f, 0.f, 0.f, 0.f, 0.f, 0.f, 0.f};
      int k = offsets[i], end = offsets[i + 1];
      for (; k + 7 < end; k += 8) {
        int r[8];
#pragma unroll
        for (int u8 = 0; u8 < 8; ++u8) r[u8] = srcidx[k + u8];
        float4 v[8];
#pragma unroll
        for (int u8 = 0; u8 < 8; ++u8)
          v[u8] = ((const float4*)(Hs + (size_t)r[u8] * 128))[ql];
#pragma unroll
        for (int u8 = 0; u8 < 8; ++u8) {
          const __half2* a = (const __half2*)&v[u8];
#pragma unroll
          for (int j = 0; j < 4; ++j) {
            float2 f = __half22float2(a[j]);
            acc[2 * j] += f.x;
            acc[2 * j + 1] += f.y;
          }
        }
      }
      for (; k + 3 < end; k += 4) {
        int r[4];
#pragma unroll
        for (int u4 = 0; u4 < 4; ++u4) r[u4] = srcidx[k + u4];
        float4 v[4];
#pragma unroll
        for (int u4 = 0; u4 < 4; ++u4)
          v[u4] = ((const float4*)(Hs + (size_t)r[u4] * 128))[ql];
#pragma unroll
        for (int u4 = 0; u4 < 4; ++u4) {
          const __half2* a = (const __half2*)&v[u4];
#pragma unroll
          for (int j = 0; j < 4; ++j) {
            float2 f = __half22float2(a[j]);
            acc[2 * j] += f.x;
            acc[2 * j + 1] += f.y;
          }
        }
      }
      for (; k < end; ++k) {
        int r0 = srcidx[k];
        float4 v0 = ((const float4*)(Hs + (size_t)r0 * 128))[ql];
        const __half2* a0 = (const __half2*)&v0;
#pragma unroll
        for (int j = 0; j < 4; ++j) {
          float2 f0 = __half22float2(a0[j]);
          acc[2 * j] += f0.x;
          acc[2 * j + 1] += f0.y;
        }
      }
      const __half2* sh = (const __half2*)&selfv;
#pragma unroll
      for (int j = 0; j < 4; ++j) {
        float2 f = __half22float2(sh[j]);
        u.h2[j] = __float22half2_rn(make_float2(di * (acc[2 * j] + f.x),
                                                di * (acc[2 * j + 1] + f.y)));
      }
    } else {
      u.f4 = make_float4(0.f, 0.f, 0.f, 0.f);
    }
    *(float4*)&ZL[nl * WT_S + ql * 8] = u.f4;  // 16B, 2-way alias only
  }
  __syncthreads();

  // phase 2: gemm2 from LDS
  int wid = t >> 6, lane = t & 63;
  int q = lane >> 4, m = lane & 15;
  int nl = wid * 16 + m;
  int node = base + nl;
  bool valid = node < N_NODES;

  half8 zfrag[4];
#pragma unroll
  for (int c = 0; c < 4; ++c) {
    zfrag[c] = *(const half8*)&ZL[nl * WT_S + 32 * c + 8 * q];
  }

#pragma unroll
  for (int f = 0; f < 8; ++f) {
    floatx4 acc = {0.f, 0.f, 0.f, 0.f};
#pragma unroll
    for (int c = 0; c < 4; ++c) {
      half8 wfrag = *(const half8*)&WL[(16 * f + m) * WT_S + 32 * c + 8 * q];
      acc = __builtin_amdgcn_mfma_f32_16x16x32_f16(wfrag, zfrag[c], acc, 0, 0, 0);
    }
    int fbase = 16 * f + 4 * q;
    float4 bias = (f < 4) ? *(const float4*)&bmu[fbase]
                          : *(const float4*)&bls[fbase - 64];
    float4 o = make_float4(acc[0] + bias.x, acc[1] + bias.y, acc[2] + bias.z,
                           acc[3] + bias.w);
    if (valid) {
      if (f < 4)
        *(float4*)&out[(size_t)node * 64 + fbase] = o;
      else
        *(float4*)&out[MU_SIZE + (size_t)node * 64 + (fbase - 64)] = o;
    }
  }
}

extern "C" void kernel_launch(void* const* d_in, const int* in_sizes, int n_in,
                              void* d_out, int out_size, void* d_ws, size_t ws_size,
                              hipStream_t stream) {
  const float* x = (const float*)d_in[0];
  const int* ei = (const int*)d_in[1];  // [2][E] int32: row=src, col=dst
  const float* W1 = (const float*)d_in[2];
  const float* b1 = (const float*)d_in[3];
  const float* Wmu = (const float*)d_in[4];
  const float* bmu = (const float*)d_in[5];
  const float* Wls = (const float*)d_in[6];
  const float* bls = (const float*)d_in[7];
  float* out = (float*)d_out;

  const int* row = ei;
  const int* col = ei + N_EDGES;

  // workspace layout (~29 MB)
  __half* bufAh = (__half*)d_ws;               // 6.4M f16 (gemm1 out, agg1 in)
  __half* bufBh = bufAh + 6400000;             // 6.4M f16 (agg1 out, fused in)
  float* dis = (float*)(bufBh + 6400000);      // 50000 f32
  int* counts = (int*)(dis + N_NODES);         // 50000 i32
  int* fillcnt = counts + N_NODES;             // 50000 i32 (contiguous w/ counts)
  int* offsets = fillcnt + N_NODES;            // 50001 i32
  int* srcidx = offsets + N_NODES + 1;         // 600000 i32
  int* blocksums = srcidx + N_EDGES;           // 200 i32
  _Float16* W1T = (_Float16*)(blocksums + 256);  // 16384 f16
  _Float16* W2T = W1T + 16384;                   // 16384 f16

  prep_zero_kernel<<<128, 256, 0, stream>>>(W1, Wmu, Wls, W1T, W2T, counts);

  int eb = (N_EDGES + 255) / 256;
  count_kernel<<<eb, 256, 0, stream>>>(col, counts, N_EDGES);
  blocksum_dis_kernel<<<SCAN_BLOCKS, 256, 0, stream>>>(counts, dis, blocksums);
  offsets_kernel<<<SCAN_BLOCKS, 256, 0, stream>>>(counts, blocksums, offsets);
  fill_kernel<<<eb, 256, 0, stream>>>(row, col, offsets, fillcnt, srcidx, N_EDGES);

  int gb = (N_NODES + 63) / 64;  // 782 blocks, one 64-node group each
  gemm1_mfma_kernel<<<gb, 256, 0, stream>>>(x, W1T, dis, (_Float16*)bufAh);
  int ab = (N_NODES + 15) / 16;  // 3125
  aggregate1_kernel<<<ab, 256, 0, stream>>>(bufAh, offsets, srcidx, dis, b1,
                                            bufBh, N_NODES);
  agg2_gemm2_kernel<<<gb, 256, 0, stream>>>(bufBh, offsets, srcidx, dis, W2T,
                                            bmu, bls, out);
}

// Round 10
// 227.899 us; speedup vs baseline: 1.0168x; 1.0168x over previous
//
#include <hip/hip_runtime.h>
#include <hip/hip_fp16.h>

// VariationalGCNEncoder: N=50000 nodes, E=600000 edges, 128->128(relu)->2x64
// out = mu (50000x64) then logstd (50000x64), flat concat.
//
// R1: hierarchical scan. R2: float4 gather aggregate, dis pre-scaling.
// R3: LDS-tile VALU GEMM. R4: fp16 aggregation operand (row=256B).
// R5: MFMA fp16 GEMM. R6: global fp16 W^T prep, swapped MFMA operands,
//     quarter-wave aggregate. R7: 1 group/block gemm, unroll-8 gather.
// R8: agg2+gemm2 fused -- REGRESSED: WL(34K)+ZL(17K) LDS -> 3 blocks/CU,
//     gather phase lost latency hiding (occ 17.6%), WL reads 8-way conflict.
// R9: fusion kept but WL dropped: phase-2 W-fragments read directly from
//     global W2T (32KB, L1-resident). LDS = ZL 17KB only -> 8 blocks/CU.

#define N_NODES 50000
#define N_EDGES 600000
#define MU_SIZE (N_NODES * 64)
#define SCAN_BLOCKS 200
#define SCAN_CHUNK 250  // SCAN_BLOCKS * SCAN_CHUNK == N_NODES
#define WT_S 136        // LDS row stride (halves), 272B: 2-way bank alias only

typedef _Float16 half8 __attribute__((ext_vector_type(8)));
typedef _Float16 half4 __attribute__((ext_vector_type(4)));
typedef float floatx4 __attribute__((ext_vector_type(4)));

union H8 { __half2 h2[4]; float4 f4; };

// Zero counts+fillcnt (contiguous 100000 ints) and build fp16 transposed
// weights: W1T[n][k] = fp16(W1[k][n]); W2T[n][k] = fp16([Wmu|Wls][k][n]).
__global__ __launch_bounds__(256) void prep_zero_kernel(const float* __restrict__ W1,
                                                        const float* __restrict__ Wmu,
                                                        const float* __restrict__ Wls,
                                                        _Float16* __restrict__ W1T,
                                                        _Float16* __restrict__ W2T,
                                                        int* __restrict__ zero_base) {
  int idx = blockIdx.x * 256 + threadIdx.x;  // grid 128 -> 32768 threads
  for (int i = idx; i < 2 * N_NODES; i += 32768) zero_base[i] = 0;
  int e = idx & 16383;
  int n = e >> 7, k = e & 127;
  if (idx < 16384) {
    W1T[e] = (_Float16)W1[k * 128 + n];
  } else {
    float w = (n < 64) ? Wmu[k * 64 + n] : Wls[k * 64 + (n - 64)];
    W2T[e] = (_Float16)w;
  }
}

__global__ __launch_bounds__(256) void count_kernel(const int* __restrict__ col,
                                                    int* __restrict__ counts, int e) {
  int i = blockIdx.x * 256 + threadIdx.x;
  if (i < e) atomicAdd(&counts[col[i]], 1);
}

// Per-block partial sums of counts (250 elems/block) + dis = rsqrt(deg+1)
__global__ __launch_bounds__(256) void blocksum_dis_kernel(const int* __restrict__ counts,
                                                           float* __restrict__ dis,
                                                           int* __restrict__ blocksums) {
  __shared__ int red[4];
  int b = blockIdx.x, t = threadIdx.x;
  int i = b * SCAN_CHUNK + t;
  int c = 0;
  if (t < SCAN_CHUNK) {
    c = counts[i];
    dis[i] = rsqrtf((float)(c + 1));  // +1 self-loop => deg >= 1 always
  }
  int s = c;
#pragma unroll
  for (int off = 32; off > 0; off >>= 1) s += __shfl_down(s, off, 64);
  if ((t & 63) == 0) red[t >> 6] = s;
  __syncthreads();
  if (t == 0) blocksums[b] = red[0] + red[1] + red[2] + red[3];
}

// Each block: scan the 200 blocksums in LDS for its exclusive base, then
// scan its own 250 counts and write exclusive offsets.
__global__ __launch_bounds__(256) void offsets_kernel(const int* __restrict__ counts,
                                                      const int* __restrict__ blocksums,
                                                      int* __restrict__ offsets) {
  __shared__ int sb[256];
  __shared__ int loc[256];
  int b = blockIdx.x, t = threadIdx.x;
  sb[t] = (t < SCAN_BLOCKS) ? blocksums[t] : 0;
  __syncthreads();
#pragma unroll
  for (int off = 1; off < 256; off <<= 1) {
    int v = (t >= off) ? sb[t - off] : 0;
    __syncthreads();
    sb[t] += v;
    __syncthreads();
  }
  int base = (b == 0) ? 0 : sb[b - 1];
  int i = b * SCAN_CHUNK + t;
  int c = (t < SCAN_CHUNK) ? counts[i] : 0;
  loc[t] = c;
  __syncthreads();
#pragma unroll
  for (int off = 1; off < 256; off <<= 1) {
    int v = (t >= off) ? loc[t - off] : 0;
    __syncthreads();
    loc[t] += v;
    __syncthreads();
  }
  if (t < SCAN_CHUNK) offsets[i] = base + loc[t] - c;  // exclusive
  if (b == SCAN_BLOCKS - 1 && t == SCAN_CHUNK - 1) offsets[N_NODES] = base + loc[t];
}

__global__ __launch_bounds__(256) void fill_kernel(const int* __restrict__ row,
                                                   const int* __restrict__ col,
                                                   const int* __restrict__ offsets,
                                                   int* __restrict__ fillcnt,
                                                   int* __restrict__ srcidx, int e) {
  int i = blockIdx.x * 256 + threadIdx.x;
  if (i < e) {
    int c = col[i];
    int pos = offsets[c] + atomicAdd(&fillcnt[c], 1);
    srcidx[pos] = row[i];
  }
}

// MFMA GEMM1, M=50000 nodes, K=128, 128 output feats. Block = 4 waves =
// 64 nodes. A = W^T tile (16 feats x 32 k, LDS), B = X^T (k-contiguous).
// D: lane(q,m) -> node m, feats 16f+4q..+3 (consecutive -> vector stores).
// out fp16: Yh[node] = dis[node] * (X @ W1)[node]
__global__ __launch_bounds__(256) void gemm1_mfma_kernel(const float* __restrict__ X,
                                                         const _Float16* __restrict__ WT,
                                                         const float* __restrict__ dis,
                                                         _Float16* __restrict__ Yh) {
  __shared__ _Float16 WL[128 * WT_S];  // 34 KB

  int t = threadIdx.x;
  for (int idx = t; idx < 128 * 16; idx += 256) {
    int n = idx >> 4, kk = (idx & 15) * 8;
    *(half8*)&WL[n * WT_S + kk] = *(const half8*)&WT[n * 128 + kk];
  }
  __syncthreads();

  int wid = t >> 6, lane = t & 63;
  int q = lane >> 4, m = lane & 15;

  int node = blockIdx.x * 64 + wid * 16 + m;
  size_t nr = (size_t)min(node, N_NODES - 1);
  bool valid = node < N_NODES;

  half8 xfrag[4];
#pragma unroll
  for (int c = 0; c < 4; ++c) {
    const float* ap = &X[nr * 128 + 32 * c + 8 * q];
    float4 a0 = *(const float4*)ap;
    float4 a1 = *(const float4*)(ap + 4);
    half8 af = {(_Float16)a0.x, (_Float16)a0.y, (_Float16)a0.z, (_Float16)a0.w,
                (_Float16)a1.x, (_Float16)a1.y, (_Float16)a1.z, (_Float16)a1.w};
    xfrag[c] = af;
  }
  float dnode = dis[nr];

#pragma unroll
  for (int f = 0; f < 8; ++f) {
    floatx4 acc = {0.f, 0.f, 0.f, 0.f};
#pragma unroll
    for (int c = 0; c < 4; ++c) {
      half8 wfrag = *(const half8*)&WL[(16 * f + m) * WT_S + 32 * c + 8 * q];
      acc = __builtin_amdgcn_mfma_f32_16x16x32_f16(wfrag, xfrag[c], acc, 0, 0, 0);
    }
    int fbase = 16 * f + 4 * q;
    if (valid) {
      half4 o = {(_Float16)(acc[0] * dnode), (_Float16)(acc[1] * dnode),
                 (_Float16)(acc[2] * dnode), (_Float16)(acc[3] * dnode)};
      *(half4*)&Yh[(size_t)node * 128 + fbase] = o;
    }
  }
}

// agg1: input rows fp16 pre-scaled Hs[i]=fp16(dis_i*H_i), fp32 accumulate.
// out[i] = fp16( di * relu(di*(sum Hs[r] + Hs[i]) + b) )   (re-scaled)
// One quarter-wave (16 lanes x 16B) per node; no cross-lane reduce.
__global__ __launch_bounds__(256) void aggregate1_kernel(const __half* __restrict__ Hs,
                                                         const int* __restrict__ offsets,
                                                         const int* __restrict__ srcidx,
                                                         const float* __restrict__ dis,
                                                         const float* __restrict__ bias,
                                                         __half* __restrict__ outH, int n) {
  int wid = threadIdx.x >> 6, lane = threadIdx.x & 63;
  int q = lane >> 4, ql = lane & 15;
  int i = blockIdx.x * 16 + wid * 4 + q;
  if (i >= n) return;
  float di = dis[i];
  float4 selfv = ((const float4*)(Hs + (size_t)i * 128))[ql];
  float acc[8] = {0.f, 0.f, 0.f, 0.f, 0.f, 0.f, 0.f, 0.f};
  int k = offsets[i], end = offsets[i + 1];
  for (; k + 7 < end; k += 8) {
    int r[8];
#pragma unroll
    for (int u = 0; u < 8; ++u) r[u] = srcidx[k + u];
    float4 v[8];
#pragma unroll
    for (int u = 0; u < 8; ++u) v[u] = ((const float4*)(Hs + (size_t)r[u] * 128))[ql];
#pragma unroll
    for (int u = 0; u < 8; ++u) {
      const __half2* a = (const __half2*)&v[u];
#pragma unroll
      for (int j = 0; j < 4; ++j) {
        float2 f = __half22float2(a[j]);
        acc[2 * j] += f.x;
        acc[2 * j + 1] += f.y;
      }
    }
  }
  for (; k + 3 < end; k += 4) {
    int r[4];
#pragma unroll
    for (int u = 0; u < 4; ++u) r[u] = srcidx[k + u];
    float4 v[4];
#pragma unroll
    for (int u = 0; u < 4; ++u) v[u] = ((const float4*)(Hs + (size_t)r[u] * 128))[ql];
#pragma unroll
    for (int u = 0; u < 4; ++u) {
      const __half2* a = (const __half2*)&v[u];
#pragma unroll
      for (int j = 0; j < 4; ++j) {
        float2 f = __half22float2(a[j]);
        acc[2 * j] += f.x;
        acc[2 * j + 1] += f.y;
      }
    }
  }
  for (; k < end; ++k) {
    int r0 = srcidx[k];
    float4 v0 = ((const float4*)(Hs + (size_t)r0 * 128))[ql];
    const __half2* a0 = (const __half2*)&v0;
#pragma unroll
    for (int j = 0; j < 4; ++j) {
      float2 f0 = __half22float2(a0[j]);
      acc[2 * j] += f0.x;
      acc[2 * j + 1] += f0.y;
    }
  }
  const __half2* sh = (const __half2*)&selfv;
  float s[8];
#pragma unroll
  for (int j = 0; j < 4; ++j) {
    float2 f = __half22float2(sh[j]);
    s[2 * j] = di * (acc[2 * j] + f.x);
    s[2 * j + 1] = di * (acc[2 * j + 1] + f.y);
  }
  float4 b0 = ((const float4*)bias)[2 * ql];
  float4 b1 = ((const float4*)bias)[2 * ql + 1];
  H8 u;
  u.h2[0] = __float22half2_rn(
      make_float2(di * fmaxf(s[0] + b0.x, 0.f), di * fmaxf(s[1] + b0.y, 0.f)));
  u.h2[1] = __float22half2_rn(
      make_float2(di * fmaxf(s[2] + b0.z, 0.f), di * fmaxf(s[3] + b0.w, 0.f)));
  u.h2[2] = __float22half2_rn(
      make_float2(di * fmaxf(s[4] + b1.x, 0.f), di * fmaxf(s[5] + b1.y, 0.f)));
  u.h2[3] = __float22half2_rn(
      make_float2(di * fmaxf(s[6] + b1.z, 0.f), di * fmaxf(s[7] + b1.w, 0.f)));
  ((float4*)(outH + (size_t)i * 128))[ql] = u.f4;
}

// FUSED agg2 + gemm2, occupancy-fixed. Block = 256 threads = 64 nodes.
// Phase 1: 16 quarter-waves aggregate 4 nodes each:
//   z_i = di*(sum Hs[r] + Hs[i]) -> fp16 into LDS ZL[nl][.]
// Phase 2: gemm2 MFMA, A-fragments (W2^T rows) read DIRECTLY FROM GLOBAL
//   (32KB, L1-resident after first touch), B = ZL rows.
// LDS = ZL 17KB only -> 8 blocks/CU (was 3 with WL staged), so the
// latency-bound gather phase keeps ~32 waves/CU of hiding.
__global__ __launch_bounds__(256) void agg2_gemm2_kernel(const __half* __restrict__ Hs,
                                                         const int* __restrict__ offsets,
                                                         const int* __restrict__ srcidx,
                                                         const float* __restrict__ dis,
                                                         const _Float16* __restrict__ W2T,
                                                         const float* __restrict__ bmu,
                                                         const float* __restrict__ bls,
                                                         float* __restrict__ out) {
  __shared__ _Float16 ZL[64 * WT_S];  // 17 KB

  int t = threadIdx.x;
  int qw = t >> 4, ql = t & 15;
  int base = blockIdx.x * 64;

  // phase 1: aggregate 64 nodes (quarter-wave per node, 4 rounds)
#pragma unroll
  for (int it = 0; it < 4; ++it) {
    int nl = qw * 4 + it;  // local node 0..63
    int i = base + nl;
    H8 u;
    if (i < N_NODES) {
      float di = dis[i];
      float4 selfv = ((const float4*)(Hs + (size_t)i * 128))[ql];
      float acc[8] = {0.f, 0.f, 0.f, 0.f, 0.f, 0.f, 0.f, 0.f};
      int k = offsets[i], end = offsets[i + 1];
      for (; k + 7 < end; k += 8) {
        int r[8];
#pragma unroll
        for (int u8 = 0; u8 < 8; ++u8) r[u8] = srcidx[k + u8];
        float4 v[8];
#pragma unroll
        for (int u8 = 0; u8 < 8; ++u8)
          v[u8] = ((const float4*)(Hs + (size_t)r[u8] * 128))[ql];
#pragma unroll
        for (int u8 = 0; u8 < 8; ++u8) {
          const __half2* a = (const __half2*)&v[u8];
#pragma unroll
          for (int j = 0; j < 4; ++j) {
            float2 f = __half22float2(a[j]);
            acc[2 * j] += f.x;
            acc[2 * j + 1] += f.y;
          }
        }
      }
      for (; k + 3 < end; k += 4) {
        int r[4];
#pragma unroll
        for (int u4 = 0; u4 < 4; ++u4) r[u4] = srcidx[k + u4];
        float4 v[4];
#pragma unroll
        for (int u4 = 0; u4 < 4; ++u4)
          v[u4] = ((const float4*)(Hs + (size_t)r[u4] * 128))[ql];
#pragma unroll
        for (int u4 = 0; u4 < 4; ++u4) {
          const __half2* a = (const __half2*)&v[u4];
#pragma unroll
          for (int j = 0; j < 4; ++j) {
            float2 f = __half22float2(a[j]);
            acc[2 * j] += f.x;
            acc[2 * j + 1] += f.y;
          }
        }
      }
      for (; k < end; ++k) {
        int r0 = srcidx[k];
        float4 v0 = ((const float4*)(Hs + (size_t)r0 * 128))[ql];
        const __half2* a0 = (const __half2*)&v0;
#pragma unroll
        for (int j = 0; j < 4; ++j) {
          float2 f0 = __half22float2(a0[j]);
          acc[2 * j] += f0.x;
          acc[2 * j + 1] += f0.y;
        }
      }
      const __half2* sh = (const __half2*)&selfv;
#pragma unroll
      for (int j = 0; j < 4; ++j) {
        float2 f = __half22float2(sh[j]);
        u.h2[j] = __float22half2_rn(make_float2(di * (acc[2 * j] + f.x),
                                                di * (acc[2 * j + 1] + f.y)));
      }
    } else {
      u.f4 = make_float4(0.f, 0.f, 0.f, 0.f);
    }
    *(float4*)&ZL[nl * WT_S + ql * 8] = u.f4;  // 16B, 2-way alias only
  }
  __syncthreads();

  // phase 2: gemm2; W-fragments straight from global (L1-hot 32KB)
  int wid = t >> 6, lane = t & 63;
  int q = lane >> 4, m = lane & 15;
  int nl = wid * 16 + m;
  int node = base + nl;
  bool valid = node < N_NODES;

  half8 zfrag[4];
#pragma unroll
  for (int c = 0; c < 4; ++c) {
    zfrag[c] = *(const half8*)&ZL[nl * WT_S + 32 * c + 8 * q];
  }

#pragma unroll
  for (int f = 0; f < 8; ++f) {
    floatx4 acc = {0.f, 0.f, 0.f, 0.f};
#pragma unroll
    for (int c = 0; c < 4; ++c) {
      half8 wfrag = *(const half8*)&W2T[(16 * f + m) * 128 + 32 * c + 8 * q];
      acc = __builtin_amdgcn_mfma_f32_16x16x32_f16(wfrag, zfrag[c], acc, 0, 0, 0);
    }
    int fbase = 16 * f + 4 * q;
    float4 bias = (f < 4) ? *(const float4*)&bmu[fbase]
                          : *(const float4*)&bls[fbase - 64];
    float4 o = make_float4(acc[0] + bias.x, acc[1] + bias.y, acc[2] + bias.z,
                           acc[3] + bias.w);
    if (valid) {
      if (f < 4)
        *(float4*)&out[(size_t)node * 64 + fbase] = o;
      else
        *(float4*)&out[MU_SIZE + (size_t)node * 64 + (fbase - 64)] = o;
    }
  }
}

extern "C" void kernel_launch(void* const* d_in, const int* in_sizes, int n_in,
                              void* d_out, int out_size, void* d_ws, size_t ws_size,
                              hipStream_t stream) {
  const float* x = (const float*)d_in[0];
  const int* ei = (const int*)d_in[1];  // [2][E] int32: row=src, col=dst
  const float* W1 = (const float*)d_in[2];
  const float* b1 = (const float*)d_in[3];
  const float* Wmu = (const float*)d_in[4];
  const float* bmu = (const float*)d_in[5];
  const float* Wls = (const float*)d_in[6];
  const float* bls = (const float*)d_in[7];
  float* out = (float*)d_out;

  const int* row = ei;
  const int* col = ei + N_EDGES;

  // workspace layout (~29 MB)
  __half* bufAh = (__half*)d_ws;               // 6.4M f16 (gemm1 out, agg1 in)
  __half* bufBh = bufAh + 6400000;             // 6.4M f16 (agg1 out, fused in)
  float* dis = (float*)(bufBh + 6400000);      // 50000 f32
  int* counts = (int*)(dis + N_NODES);         // 50000 i32
  int* fillcnt = counts + N_NODES;             // 50000 i32 (contiguous w/ counts)
  int* offsets = fillcnt + N_NODES;            // 50001 i32
  int* srcidx = offsets + N_NODES + 1;         // 600000 i32
  int* blocksums = srcidx + N_EDGES;           // 200 i32
  _Float16* W1T = (_Float16*)(blocksums + 256);  // 16384 f16
  _Float16* W2T = W1T + 16384;                   // 16384 f16

  prep_zero_kernel<<<128, 256, 0, stream>>>(W1, Wmu, Wls, W1T, W2T, counts);

  int eb = (N_EDGES + 255) / 256;
  count_kernel<<<eb, 256, 0, stream>>>(col, counts, N_EDGES);
  blocksum_dis_kernel<<<SCAN_BLOCKS, 256, 0, stream>>>(counts, dis, blocksums);
  offsets_kernel<<<SCAN_BLOCKS, 256, 0, stream>>>(counts, blocksums, offsets);
  fill_kernel<<<eb, 256, 0, stream>>>(row, col, offsets, fillcnt, srcidx, N_EDGES);

  int gb = (N_NODES + 63) / 64;  // 782 blocks, one 64-node group each
  gemm1_mfma_kernel<<<gb, 256, 0, stream>>>(x, W1T, dis, (_Float16*)bufAh);
  int ab = (N_NODES + 15) / 16;  // 3125
  aggregate1_kernel<<<ab, 256, 0, stream>>>(bufAh, offsets, srcidx, dis, b1,
                                            bufBh, N_NODES);
  agg2_gemm2_kernel<<<gb, 256, 0, stream>>>(bufBh, offsets, srcidx, dis, W2T,
                                            bmu, bls, out);
}

// Round 11
// 222.434 us; speedup vs baseline: 1.0417x; 1.0246x over previous
//
#include <hip/hip_runtime.h>
#include <hip/hip_fp16.h>

// VariationalGCNEncoder: N=50000 nodes, E=600000 edges, 128->128(relu)->2x64
// out = mu (50000x64) then logstd (50000x64), flat concat.
//
// R1: hierarchical scan (78us -> ~5us).
// R2: aggregate latency fix: float4 gather, half-wave/edge, dis pre-scaling.
// R3: LDS-tile VALU GEMM. R4: fp16 aggregation operand (row=256B).
// R5: MFMA fp16 GEMM (v_mfma_f32_16x16x32_f16).
// R6: global fp16 W^T prep (conflict-free staging), swapped MFMA operands
//     (vector stores), quarter-wave aggregate without shuffles.  <- BEST: 221.6us
// R7: micro-opts (1 group/block, unroll-8, merged prep): neutral (223.3).
// R8: agg2+gemm2 fused w/ WL in LDS: REGRESSED (231.7; occ 17.6%, conflicts).
// R9: fusion w/ W from global: still worse (227.9) - barrier couples the
//     latency-bound gather to MFMA; fusion's 25.6MB saving < stall cost.
// R10: REVERT to R6 exact structure (best measured).

#define N_NODES 50000
#define N_EDGES 600000
#define MU_SIZE (N_NODES * 64)
#define SCAN_BLOCKS 200
#define SCAN_CHUNK 250  // SCAN_BLOCKS * SCAN_CHUNK == N_NODES
#define WT_S 136        // LDS row stride (halves), 272B: 16B-aligned rows

typedef _Float16 half8 __attribute__((ext_vector_type(8)));
typedef _Float16 half4 __attribute__((ext_vector_type(4)));
typedef float floatx4 __attribute__((ext_vector_type(4)));

union H8 { __half2 h2[4]; float4 f4; };

__global__ __launch_bounds__(256) void count_kernel(const int* __restrict__ col,
                                                    int* __restrict__ counts, int e) {
  int i = blockIdx.x * 256 + threadIdx.x;
  if (i < e) atomicAdd(&counts[col[i]], 1);
}

// Per-block partial sums of counts (250 elems/block) + dis = rsqrt(deg+1)
__global__ __launch_bounds__(256) void blocksum_dis_kernel(const int* __restrict__ counts,
                                                           float* __restrict__ dis,
                                                           int* __restrict__ blocksums) {
  __shared__ int red[4];
  int b = blockIdx.x, t = threadIdx.x;
  int i = b * SCAN_CHUNK + t;
  int c = 0;
  if (t < SCAN_CHUNK) {
    c = counts[i];
    dis[i] = rsqrtf((float)(c + 1));  // +1 self-loop => deg >= 1 always
  }
  int s = c;
#pragma unroll
  for (int off = 32; off > 0; off >>= 1) s += __shfl_down(s, off, 64);
  if ((t & 63) == 0) red[t >> 6] = s;
  __syncthreads();
  if (t == 0) blocksums[b] = red[0] + red[1] + red[2] + red[3];
}

// Each block: scan the 200 blocksums in LDS for its exclusive base, then
// scan its own 250 counts and write exclusive offsets.
__global__ __launch_bounds__(256) void offsets_kernel(const int* __restrict__ counts,
                                                      const int* __restrict__ blocksums,
                                                      int* __restrict__ offsets) {
  __shared__ int sb[256];
  __shared__ int loc[256];
  int b = blockIdx.x, t = threadIdx.x;
  sb[t] = (t < SCAN_BLOCKS) ? blocksums[t] : 0;
  __syncthreads();
#pragma unroll
  for (int off = 1; off < 256; off <<= 1) {
    int v = (t >= off) ? sb[t - off] : 0;
    __syncthreads();
    sb[t] += v;
    __syncthreads();
  }
  int base = (b == 0) ? 0 : sb[b - 1];
  int i = b * SCAN_CHUNK + t;
  int c = (t < SCAN_CHUNK) ? counts[i] : 0;
  loc[t] = c;
  __syncthreads();
#pragma unroll
  for (int off = 1; off < 256; off <<= 1) {
    int v = (t >= off) ? loc[t - off] : 0;
    __syncthreads();
    loc[t] += v;
    __syncthreads();
  }
  if (t < SCAN_CHUNK) offsets[i] = base + loc[t] - c;  // exclusive
  if (b == SCAN_BLOCKS - 1 && t == SCAN_CHUNK - 1) offsets[N_NODES] = base + loc[t];
}

__global__ __launch_bounds__(256) void fill_kernel(const int* __restrict__ row,
                                                   const int* __restrict__ col,
                                                   const int* __restrict__ offsets,
                                                   int* __restrict__ fillcnt,
                                                   int* __restrict__ srcidx, int e) {
  int i = blockIdx.x * 256 + threadIdx.x;
  if (i < e) {
    int c = col[i];
    int pos = offsets[c] + atomicAdd(&fillcnt[c], 1);
    srcidx[pos] = row[i];
  }
}

// Build fp16 transposed weights in global once:
// W1T[n][k] = fp16(W1[k][n]); W2T[n][k] = fp16(n<64 ? Wmu[k][n] : Wls[k][n-64])
__global__ __launch_bounds__(256) void prep_wt_kernel(const float* __restrict__ W1,
                                                      const float* __restrict__ Wmu,
                                                      const float* __restrict__ Wls,
                                                      _Float16* __restrict__ W1T,
                                                      _Float16* __restrict__ W2T) {
  int idx = blockIdx.x * 256 + threadIdx.x;  // grid 128 -> 32768
  int e = idx & 16383;
  int n = e >> 7, k = e & 127;
  if (idx < 16384) {
    W1T[e] = (_Float16)W1[k * 128 + n];
  } else {
    float w = (n < 64) ? Wmu[k * 64 + n] : Wls[k * 64 + (n - 64)];
    W2T[e] = (_Float16)w;
  }
}

// MFMA GEMM, M=50000 nodes, K=128, 128 output feats. Block = 4 waves;
// each wave-iteration covers 16 nodes x 128 feats.
// A = W^T tile (16 feats x 32 k, from LDS), B = X^T (32 k x 16 nodes;
// k-contiguous == X row-major -> direct b128).
// D: lane(q,m) -> node m, feats 16f+4q..+3 (consecutive -> vector stores).
// SPLIT=false (gemm1): B from fp32 X (cvt), out fp16 Yh = dis[node]*(X@W1)
// SPLIT=true  (gemm2): B from fp16 Xh, out fp32 mu/logstd split + bias.
template <bool SPLIT>
__global__ __launch_bounds__(256) void gemm_mfma_kernel(const float* __restrict__ X,
                                                        const _Float16* __restrict__ Xh,
                                                        const _Float16* __restrict__ WT,
                                                        const float* __restrict__ dis,
                                                        const float* __restrict__ ba,
                                                        const float* __restrict__ bb,
                                                        _Float16* __restrict__ Yh,
                                                        float* __restrict__ Yf) {
  __shared__ _Float16 WL[128 * WT_S];  // 34 KB

  int t = threadIdx.x;
  // stage W^T: coalesced b128 global reads, conflict-free LDS writes
  for (int idx = t; idx < 128 * 16; idx += 256) {
    int n = idx >> 4, kk = (idx & 15) * 8;
    *(half8*)&WL[n * WT_S + kk] = *(const half8*)&WT[n * 128 + kk];
  }
  __syncthreads();

  int wid = t >> 6, lane = t & 63;
  int q = lane >> 4, m = lane & 15;
  const int ngroups = (N_NODES + 63) / 64;  // 782

  for (int g64 = blockIdx.x; g64 < ngroups; g64 += gridDim.x) {
    int node = g64 * 64 + wid * 16 + m;
    size_t nr = (size_t)min(node, N_NODES - 1);
    bool valid = node < N_NODES;

    // B fragments: lane (q,m) holds X[node][32c + 8q + j], j=0..7
    half8 xfrag[4];
    if (!SPLIT) {
#pragma unroll
      for (int c = 0; c < 4; ++c) {
        const float* ap = &X[nr * 128 + 32 * c + 8 * q];
        float4 a0 = *(const float4*)ap;
        float4 a1 = *(const float4*)(ap + 4);
        half8 af = {(_Float16)a0.x, (_Float16)a0.y, (_Float16)a0.z, (_Float16)a0.w,
                    (_Float16)a1.x, (_Float16)a1.y, (_Float16)a1.z, (_Float16)a1.w};
        xfrag[c] = af;
      }
    } else {
#pragma unroll
      for (int c = 0; c < 4; ++c) {
        xfrag[c] = *(const half8*)&Xh[nr * 128 + 32 * c + 8 * q];
      }
    }
    float dnode = SPLIT ? 0.f : dis[nr];

#pragma unroll
    for (int f = 0; f < 8; ++f) {  // feat tile: feats 16f..16f+15
      floatx4 acc = {0.f, 0.f, 0.f, 0.f};
#pragma unroll
      for (int c = 0; c < 4; ++c) {
        half8 wfrag = *(const half8*)&WL[(16 * f + m) * WT_S + 32 * c + 8 * q];
        acc = __builtin_amdgcn_mfma_f32_16x16x32_f16(wfrag, xfrag[c], acc, 0, 0, 0);
      }
      int fbase = 16 * f + 4 * q;  // 4 consecutive feats for this lane
      if (!SPLIT) {
        if (valid) {
          half4 o = {(_Float16)(acc[0] * dnode), (_Float16)(acc[1] * dnode),
                     (_Float16)(acc[2] * dnode), (_Float16)(acc[3] * dnode)};
          *(half4*)&Yh[(size_t)node * 128 + fbase] = o;
        }
      } else {
        // f<4 -> mu cols (fbase<64), f>=4 -> logstd (wave-uniform branch)
        float4 bias = (f < 4) ? *(const float4*)&ba[fbase]
                              : *(const float4*)&bb[fbase - 64];
        float4 o = make_float4(acc[0] + bias.x, acc[1] + bias.y, acc[2] + bias.z,
                               acc[3] + bias.w);
        if (valid) {
          if (f < 4)
            *(float4*)&Yf[(size_t)node * 64 + fbase] = o;
          else
            *(float4*)&Yf[MU_SIZE + (size_t)node * 64 + (fbase - 64)] = o;
        }
      }
    }
  }
}

// Input rows fp16, pre-scaled: Hs[i] = fp16(dis[i] * H[i]). fp32 accumulate.
// One quarter-wave (16 lanes x float4-of-halves) per node; no cross-lane
// reduce; edge loop unrolled x4 -> 16 gathers in flight per wave.
// BIAS_RELU=true:  out[i] = fp16( di * relu(di*(sum Hs[r] + Hs[i]) + b) )
// BIAS_RELU=false: out[i] = fp16( di * (sum Hs[r] + Hs[i]) )
template <bool BIAS_RELU>
__global__ __launch_bounds__(256) void aggregate_kernel(const __half* __restrict__ Hs,
                                                        const int* __restrict__ offsets,
                                                        const int* __restrict__ srcidx,
                                                        const float* __restrict__ dis,
                                                        const float* __restrict__ bias,
                                                        __half* __restrict__ outH, int n) {
  int wid = threadIdx.x >> 6, lane = threadIdx.x & 63;
  int q = lane >> 4, ql = lane & 15;
  int i = blockIdx.x * 16 + wid * 4 + q;
  if (i >= n) return;
  float di = dis[i];
  float4 selfv = ((const float4*)(Hs + (size_t)i * 128))[ql];
  float acc[8] = {0.f, 0.f, 0.f, 0.f, 0.f, 0.f, 0.f, 0.f};
  int k = offsets[i], end = offsets[i + 1];
  for (; k + 3 < end; k += 4) {
    int r0 = srcidx[k];
    int r1 = srcidx[k + 1];
    int r2 = srcidx[k + 2];
    int r3 = srcidx[k + 3];
    float4 v0 = ((const float4*)(Hs + (size_t)r0 * 128))[ql];
    float4 v1 = ((const float4*)(Hs + (size_t)r1 * 128))[ql];
    float4 v2 = ((const float4*)(Hs + (size_t)r2 * 128))[ql];
    float4 v3 = ((const float4*)(Hs + (size_t)r3 * 128))[ql];
    const __half2* a0 = (const __half2*)&v0;
    const __half2* a1 = (const __half2*)&v1;
    const __half2* a2 = (const __half2*)&v2;
    const __half2* a3 = (const __half2*)&v3;
#pragma unroll
    for (int j = 0; j < 4; ++j) {
      float2 f0 = __half22float2(a0[j]);
      float2 f1 = __half22float2(a1[j]);
      float2 f2 = __half22float2(a2[j]);
      float2 f3 = __half22float2(a3[j]);
      acc[2 * j] += (f0.x + f1.x) + (f2.x + f3.x);
      acc[2 * j + 1] += (f0.y + f1.y) + (f2.y + f3.y);
    }
  }
  for (; k < end; ++k) {
    int r0 = srcidx[k];
    float4 v0 = ((const float4*)(Hs + (size_t)r0 * 128))[ql];
    const __half2* a0 = (const __half2*)&v0;
#pragma unroll
    for (int j = 0; j < 4; ++j) {
      float2 f0 = __half22float2(a0[j]);
      acc[2 * j] += f0.x;
      acc[2 * j + 1] += f0.y;
    }
  }
  const __half2* sh = (const __half2*)&selfv;
  float s[8];
#pragma unroll
  for (int j = 0; j < 4; ++j) {
    float2 f = __half22float2(sh[j]);
    s[2 * j] = di * (acc[2 * j] + f.x);
    s[2 * j + 1] = di * (acc[2 * j + 1] + f.y);
  }
  H8 u;
  if (BIAS_RELU) {
    float4 b0 = ((const float4*)bias)[2 * ql];
    float4 b1 = ((const float4*)bias)[2 * ql + 1];
    u.h2[0] = __float22half2_rn(
        make_float2(di * fmaxf(s[0] + b0.x, 0.f), di * fmaxf(s[1] + b0.y, 0.f)));
    u.h2[1] = __float22half2_rn(
        make_float2(di * fmaxf(s[2] + b0.z, 0.f), di * fmaxf(s[3] + b0.w, 0.f)));
    u.h2[2] = __float22half2_rn(
        make_float2(di * fmaxf(s[4] + b1.x, 0.f), di * fmaxf(s[5] + b1.y, 0.f)));
    u.h2[3] = __float22half2_rn(
        make_float2(di * fmaxf(s[6] + b1.z, 0.f), di * fmaxf(s[7] + b1.w, 0.f)));
  } else {
    u.h2[0] = __float22half2_rn(make_float2(s[0], s[1]));
    u.h2[1] = __float22half2_rn(make_float2(s[2], s[3]));
    u.h2[2] = __float22half2_rn(make_float2(s[4], s[5]));
    u.h2[3] = __float22half2_rn(make_float2(s[6], s[7]));
  }
  ((float4*)(outH + (size_t)i * 128))[ql] = u.f4;
}

extern "C" void kernel_launch(void* const* d_in, const int* in_sizes, int n_in,
                              void* d_out, int out_size, void* d_ws, size_t ws_size,
                              hipStream_t stream) {
  const float* x = (const float*)d_in[0];
  const int* ei = (const int*)d_in[1];  // [2][E] int32: row=src, col=dst
  const float* W1 = (const float*)d_in[2];
  const float* b1 = (const float*)d_in[3];
  const float* Wmu = (const float*)d_in[4];
  const float* bmu = (const float*)d_in[5];
  const float* Wls = (const float*)d_in[6];
  const float* bls = (const float*)d_in[7];
  float* out = (float*)d_out;

  const int* row = ei;
  const int* col = ei + N_EDGES;

  // workspace layout (~42 MB)
  __half* bufAh = (__half*)d_ws;               // 6.4M f16 (gemm1 out, agg1 in)
  __half* bufBh = bufAh + 6400000;             // 6.4M f16 (agg1 out, agg2 in)
  __half* bufCh = bufBh + 6400000;             // 6.4M f16 (agg2 out, gemm2 in)
  float* dis = (float*)(bufCh + 6400000);      // 50000 f32
  int* counts = (int*)(dis + N_NODES);         // 50000 i32
  int* fillcnt = counts + N_NODES;             // 50000 i32
  int* offsets = fillcnt + N_NODES;            // 50001 i32
  int* srcidx = offsets + N_NODES + 1;         // 600000 i32
  int* blocksums = srcidx + N_EDGES;           // 200 i32
  _Float16* W1T = (_Float16*)(blocksums + 256);  // 16384 f16
  _Float16* W2T = W1T + 16384;                   // 16384 f16

  hipMemsetAsync(counts, 0, 2 * N_NODES * sizeof(int), stream);  // counts + fillcnt

  prep_wt_kernel<<<128, 256, 0, stream>>>(W1, Wmu, Wls, W1T, W2T);

  int eb = (N_EDGES + 255) / 256;
  count_kernel<<<eb, 256, 0, stream>>>(col, counts, N_EDGES);
  blocksum_dis_kernel<<<SCAN_BLOCKS, 256, 0, stream>>>(counts, dis, blocksums);
  offsets_kernel<<<SCAN_BLOCKS, 256, 0, stream>>>(counts, blocksums, offsets);
  fill_kernel<<<eb, 256, 0, stream>>>(row, col, offsets, fillcnt, srcidx, N_EDGES);

  gemm_mfma_kernel<false><<<512, 256, 0, stream>>>(x, nullptr, W1T, dis, nullptr, nullptr,
                                                   (_Float16*)bufAh, nullptr);
  int ab = (N_NODES + 15) / 16;  // 3125
  aggregate_kernel<true><<<ab, 256, 0, stream>>>(bufAh, offsets, srcidx, dis, b1,
                                                 bufBh, N_NODES);
  aggregate_kernel<false><<<ab, 256, 0, stream>>>(bufBh, offsets, srcidx, dis,
                                                  nullptr, bufCh, N_NODES);
  gemm_mfma_kernel<true><<<512, 256, 0, stream>>>(nullptr, (const _Float16*)bufCh, W2T,
                                                  nullptr, bmu, bls, nullptr, out);
}